// Round 8
// baseline (207.799 us; speedup 1.0000x reference)
//
#include <hip/hip_runtime.h>
#include <stdint.h>

#define B_ 10000
#define T_ 80
#define E_ 100
#define U_ 64

typedef __attribute__((ext_vector_type(8))) short bf16x8;
typedef __attribute__((ext_vector_type(4))) float f32x4;

union FragU { bf16x8 v; uint32_t u[4]; short s[8]; };

__device__ __forceinline__ void split_bf16(float w, short& hi, short& lo) {
    uint32_t wb  = __float_as_uint(w);
    uint32_t hib = wb & 0xFFFF0000u;
    float rem = w - __uint_as_float(hib);   // exact
    hi = (short)(hib >> 16);
    lo = (short)(__float_as_uint(rem) >> 16);
}

__device__ __forceinline__ short bf16_rne(float w) {
    uint32_t u = __float_as_uint(w);
    uint32_t r = (u + 0x7FFFu + ((u >> 16) & 1u)) >> 16;
    return (short)r;
}

__device__ __forceinline__ float tanh_fast(float v) {
    float e  = __expf(2.0f * fabsf(v));     // overflow -> inf -> tanh -> 1
    float r  = __builtin_amdgcn_rcpf(e + 1.0f);
    float tn = fmaf(-2.0f, r, 1.0f);
    uint32_t res = (__float_as_uint(tn) & 0x7FFFFFFFu) | (__float_as_uint(v) & 0x80000000u);
    return __uint_as_float(res);
}

__device__ __forceinline__ float sigmoid_f(float logit) {
    if (logit >= 0.0f) return __builtin_amdgcn_rcpf(1.0f + __expf(-logit));
    float e = __expf(logit);
    return e * __builtin_amdgcn_rcpf(1.0f + e);
}

// cross-wave barrier that does NOT drain vmcnt: in-flight global prefetch survives.
// lgkmcnt(0) makes this wave's LDS writes visible before s_barrier (cross-wave h exchange).
__device__ __forceinline__ void barrier_lgkm() {
    asm volatile("s_waitcnt lgkmcnt(0)\n\ts_barrier" ::: "memory");
}

// gather 28 valid floats of one emb row slice for lane (q,*)
__device__ __forceinline__ void gather_x(const float* __restrict__ erow, int q, f32x4 xf[7]) {
    #pragma unroll
    for (int kk = 0; kk < 3; ++kk) {
        const int k0 = 8 * q + 32 * kk;            // max 88; +7 = 95 < 100
        xf[2 * kk]     = *(const f32x4*)(erow + k0);
        xf[2 * kk + 1] = *(const f32x4*)(erow + k0 + 4);
    }
    xf[6] = *(const f32x4*)(erow + 96);
}

// 28 f32 -> 4 bf16 A-fragments (truncation pack)
__device__ __forceinline__ void cvt_x(const f32x4 xf[7], FragU ax[4]) {
    #pragma unroll
    for (int kk = 0; kk < 3; ++kk) {
        ax[kk].u[0] = __builtin_amdgcn_perm(__float_as_uint(xf[2*kk][1]),   __float_as_uint(xf[2*kk][0]),   0x07060302u);
        ax[kk].u[1] = __builtin_amdgcn_perm(__float_as_uint(xf[2*kk][3]),   __float_as_uint(xf[2*kk][2]),   0x07060302u);
        ax[kk].u[2] = __builtin_amdgcn_perm(__float_as_uint(xf[2*kk+1][1]), __float_as_uint(xf[2*kk+1][0]), 0x07060302u);
        ax[kk].u[3] = __builtin_amdgcn_perm(__float_as_uint(xf[2*kk+1][3]), __float_as_uint(xf[2*kk+1][2]), 0x07060302u);
    }
    ax[3].u[0] = __builtin_amdgcn_perm(__float_as_uint(xf[6][1]), __float_as_uint(xf[6][0]), 0x07060302u);
    ax[3].u[1] = __builtin_amdgcn_perm(__float_as_uint(xf[6][3]), __float_as_uint(xf[6][2]), 0x07060302u);
    ax[3].u[2] = ax[3].u[0];   // k>=100 rows of Wx frag are zero
    ax[3].u[3] = ax[3].u[1];
}

// ============ fused RNN: 4 waves / 16 rows; wave w owns units 16w..16w+15 ============
// h exchanged via double-buffered packed(hi|lo)-bf16 LDS; ONE lgkm-only barrier per step.
__global__ __launch_bounds__(256, 3)
void rnn_nsplit(const int* __restrict__ tokens, const float* __restrict__ emb,
                const float* __restrict__ Wx, const float* __restrict__ Wh,
                const float* __restrict__ bias, const float* __restrict__ Wfc,
                const float* __restrict__ bfc, float* __restrict__ out)
{
    __shared__ __align__(16) uint32_t H2[2][16 * 64];  // packed (hi<<16|lo) h, XOR-swizzled
    __shared__ int   toks[16 * T_];
    __shared__ float red[4][16];

    const int tid = threadIdx.x;
    const int w   = tid >> 6;          // wave id = n-slice
    const int l   = tid & 63;
    const int q   = l >> 4, p = l & 15;
    const int R0  = blockIdx.x * 16;
    const int swz = (p & 7) << 2;

    for (int i = tid; i < 16 * T_; i += 256) toks[i] = tokens[R0 * T_ + i];

    // ---- Wx fragments for n=w: 1-term RNE ----
    FragU wxh[4];
    #pragma unroll
    for (int kk = 0; kk < 4; ++kk)
        #pragma unroll
        for (int j = 0; j < 8; ++j) {
            int k = 8 * q + j + 32 * kk;
            float v = (k < E_) ? Wx[k * U_ + 16 * w + p] : 0.0f;
            wxh[kk].s[j] = bf16_rne(v);
        }
    // ---- Wh fragments for n=w: exact hi/lo (3-term recurrence) ----
    FragU whh[2], whl[2];
    #pragma unroll
    for (int kk = 0; kk < 2; ++kk)
        #pragma unroll
        for (int j = 0; j < 8; ++j) {
            float v = Wh[(8 * q + j + 32 * kk) * U_ + 16 * w + p];
            split_bf16(v, whh[kk].s[j], whl[kk].s[j]);
        }

    const float bv = bias[16 * w + p];
    const float wf = Wfc[16 * w + p];
    const f32x4 bv4   = {bv, bv, bv, bv};
    const f32x4 zero4 = {0.0f, 0.0f, 0.0f, 0.0f};

    // h(0) = 0 in buffer 0
    for (int i = tid; i < 16 * 64; i += 256) H2[0][i] = 0u;
    __syncthreads();                                   // full barrier once (toks + H2[0])

    // ---- pipeline prologue: x(0) ready, x(1) in flight ----
    f32x4 X[7];
    FragU axA[4], axB[4];
    gather_x(emb + (size_t)toks[p * T_ + 0] * E_, q, X);
    cvt_x(X, axA);
    gather_x(emb + (size_t)toks[p * T_ + 1] * E_, q, X);
    int tokc = toks[p * T_ + 2];
    int tokn;

    float hl[4];

#define STEP(AXC, AXN, TCUR)                                                        \
{                                                                                   \
    barrier_lgkm();   /* prev step's h-writes visible; vmcnt prefetch untouched */  \
    /* issue h(t-1) reads immediately (latency overlaps cvt/gather below) */        \
    const uint32_t* Hrow = H2[(TCUR) & 1] + p * 64;                                 \
    uint4 hr0 = *(const uint4*)(Hrow + ((8 * q)      ^ swz));                       \
    uint4 hr1 = *(const uint4*)(Hrow + ((8 * q + 4)  ^ swz));                       \
    uint4 hr2 = *(const uint4*)(Hrow + ((8 * q + 32) ^ swz));                       \
    uint4 hr3 = *(const uint4*)(Hrow + ((8 * q + 36) ^ swz));                       \
    /* x(TCUR+1) arrived during previous step */                                    \
    cvt_x(X, AXN);                                                                  \
    /* issue gather x(TCUR+2) */                                                    \
    gather_x(emb + (size_t)tokc * E_, q, X);                                        \
    { int ti = (TCUR) + 3; if (ti > T_ - 1) ti = T_ - 1;                            \
      tokn = toks[p * T_ + ti]; }                                                   \
    /* unpack h fragments */                                                        \
    FragU ah0, ah1, al0, al1;                                                       \
    ah0.u[0] = __builtin_amdgcn_perm(hr0.y, hr0.x, 0x07060302u);                    \
    ah0.u[1] = __builtin_amdgcn_perm(hr0.w, hr0.z, 0x07060302u);                    \
    ah0.u[2] = __builtin_amdgcn_perm(hr1.y, hr1.x, 0x07060302u);                    \
    ah0.u[3] = __builtin_amdgcn_perm(hr1.w, hr1.z, 0x07060302u);                    \
    al0.u[0] = __builtin_amdgcn_perm(hr0.y, hr0.x, 0x05040100u);                    \
    al0.u[1] = __builtin_amdgcn_perm(hr0.w, hr0.z, 0x05040100u);                    \
    al0.u[2] = __builtin_amdgcn_perm(hr1.y, hr1.x, 0x05040100u);                    \
    al0.u[3] = __builtin_amdgcn_perm(hr1.w, hr1.z, 0x05040100u);                    \
    ah1.u[0] = __builtin_amdgcn_perm(hr2.y, hr2.x, 0x07060302u);                    \
    ah1.u[1] = __builtin_amdgcn_perm(hr2.w, hr2.z, 0x07060302u);                    \
    ah1.u[2] = __builtin_amdgcn_perm(hr3.y, hr3.x, 0x07060302u);                    \
    ah1.u[3] = __builtin_amdgcn_perm(hr3.w, hr3.z, 0x07060302u);                    \
    al1.u[0] = __builtin_amdgcn_perm(hr2.y, hr2.x, 0x05040100u);                    \
    al1.u[1] = __builtin_amdgcn_perm(hr2.w, hr2.z, 0x05040100u);                    \
    al1.u[2] = __builtin_amdgcn_perm(hr3.y, hr3.x, 0x05040100u);                    \
    al1.u[3] = __builtin_amdgcn_perm(hr3.w, hr3.z, 0x05040100u);                    \
    /* 3 MFMA chains, depth <= 4 */                                                 \
    f32x4 cx = __builtin_amdgcn_mfma_f32_16x16x32_bf16(AXC[0].v, wxh[0].v, bv4, 0, 0, 0);   \
    cx = __builtin_amdgcn_mfma_f32_16x16x32_bf16(AXC[1].v, wxh[1].v, cx, 0, 0, 0);          \
    cx = __builtin_amdgcn_mfma_f32_16x16x32_bf16(AXC[2].v, wxh[2].v, cx, 0, 0, 0);          \
    cx = __builtin_amdgcn_mfma_f32_16x16x32_bf16(AXC[3].v, wxh[3].v, cx, 0, 0, 0);          \
    f32x4 cy = __builtin_amdgcn_mfma_f32_16x16x32_bf16(ah0.v, whh[0].v, zero4, 0, 0, 0);    \
    cy = __builtin_amdgcn_mfma_f32_16x16x32_bf16(ah1.v, whh[1].v, cy, 0, 0, 0);             \
    cy = __builtin_amdgcn_mfma_f32_16x16x32_bf16(ah0.v, whl[0].v, cy, 0, 0, 0);             \
    f32x4 cz = __builtin_amdgcn_mfma_f32_16x16x32_bf16(al0.v, whh[0].v, zero4, 0, 0, 0);    \
    cz = __builtin_amdgcn_mfma_f32_16x16x32_bf16(al1.v, whh[1].v, cz, 0, 0, 0);             \
    cz = __builtin_amdgcn_mfma_f32_16x16x32_bf16(ah1.v, whl[1].v, cz, 0, 0, 0);             \
    f32x4 acc = (cx + cy) + cz;                                                     \
    /* tanh + pack + write h(t) to other buffer */                                  \
    uint32_t* Hw = H2[((TCUR) + 1) & 1];                                            \
    _Pragma("unroll")                                                               \
    for (int r = 0; r < 4; ++r) {                                                   \
        float h = tanh_fast(acc[r]);                                                \
        hl[r] = h;                                                                  \
        uint32_t hb  = __float_as_uint(h);                                          \
        uint32_t hib = hb & 0xFFFF0000u;                                            \
        float rem = h - __uint_as_float(hib);                                       \
        uint32_t packed = hib | (__float_as_uint(rem) >> 16);                       \
        int row = 4 * q + r;                                                        \
        Hw[row * 64 + ((16 * w + p) ^ ((row & 7) << 2))] = packed;                  \
    }                                                                               \
    tokc = tokn;                                                                    \
}

    for (int t = 0; t < T_; t += 2) {
        STEP(axA, axB, t)
        STEP(axB, axA, t + 1)
    }
#undef STEP

    // ---- logits: per-row dot over this wave's 16 units, then cross-wave sum ----
    #pragma unroll
    for (int r = 0; r < 4; ++r) {
        float part = hl[r] * wf;
        part += __shfl_xor(part, 1);
        part += __shfl_xor(part, 2);
        part += __shfl_xor(part, 4);
        part += __shfl_xor(part, 8);
        if (p == 0) red[w][4 * q + r] = part;
    }
    __syncthreads();
    if (tid < 16) {
        float logit = red[0][tid] + red[1][tid] + red[2][tid] + red[3][tid] + bfc[0];
        out[R0 + tid] = sigmoid_f(logit);
    }
}

extern "C" void kernel_launch(void* const* d_in, const int* in_sizes, int n_in,
                              void* d_out, int out_size, void* d_ws, size_t ws_size,
                              hipStream_t stream) {
    const int*   tokens = (const int*)  d_in[0];
    const float* emb    = (const float*)d_in[1];
    const float* Wx     = (const float*)d_in[2];
    const float* Wh     = (const float*)d_in[3];
    const float* b      = (const float*)d_in[4];
    const float* Wfc    = (const float*)d_in[5];
    const float* bfc    = (const float*)d_in[6];
    float* out          = (float*)d_out;

    rnn_nsplit<<<B_ / 16, 256, 0, stream>>>(tokens, emb, Wx, Wh, b, Wfc, bfc, out);
}

// Round 9
// 144.558 us; speedup vs baseline: 1.4375x; 1.4375x over previous
//
#include <hip/hip_runtime.h>
#include <stdint.h>

#define B_ 10000
#define T_ 80
#define E_ 100
#define U_ 64

typedef __attribute__((ext_vector_type(8))) short bf16x8;
typedef __attribute__((ext_vector_type(4))) float f32x4;

union FragU { bf16x8 v; uint32_t u[4]; short s[8]; };
union LdU  { uint4 q4; bf16x8 v; };

__device__ __forceinline__ void split_bf16(float w, short& hi, short& lo) {
    uint32_t wb  = __float_as_uint(w);
    uint32_t hib = wb & 0xFFFF0000u;
    float rem = w - __uint_as_float(hib);   // exact
    hi = (short)(hib >> 16);
    lo = (short)(__float_as_uint(rem) >> 16);
}

__device__ __forceinline__ short bf16_rne(float w) {
    uint32_t u = __float_as_uint(w);
    uint32_t r = (u + 0x7FFFu + ((u >> 16) & 1u)) >> 16;
    return (short)r;
}

__device__ __forceinline__ float tanh_fast(float v) {
    float e  = __expf(2.0f * fabsf(v));     // overflow -> inf -> tanh -> 1
    float r  = __builtin_amdgcn_rcpf(e + 1.0f);
    float tn = fmaf(-2.0f, r, 1.0f);
    uint32_t res = (__float_as_uint(tn) & 0x7FFFFFFFu) | (__float_as_uint(v) & 0x80000000u);
    return __uint_as_float(res);
}

__device__ __forceinline__ float sigmoid_f(float logit) {
    if (logit >= 0.0f) return __builtin_amdgcn_rcpf(1.0f + __expf(-logit));
    float e = __expf(logit);
    return e * __builtin_amdgcn_rcpf(1.0f + e);
}

// gather 28 valid floats of one emb row slice for lane (q,*)
__device__ __forceinline__ void gather_x(const float* __restrict__ erow, int q, f32x4 xf[7]) {
    #pragma unroll
    for (int kk = 0; kk < 3; ++kk) {
        const int k0 = 8 * q + 32 * kk;            // max 88; +7 = 95 < 100
        xf[2 * kk]     = *(const f32x4*)(erow + k0);
        xf[2 * kk + 1] = *(const f32x4*)(erow + k0 + 4);
    }
    xf[6] = *(const f32x4*)(erow + 96);
}

// 28 f32 -> 4 bf16 A-fragments (truncation pack)
__device__ __forceinline__ void cvt_x(const f32x4 xf[7], FragU ax[4]) {
    #pragma unroll
    for (int kk = 0; kk < 3; ++kk) {
        ax[kk].u[0] = __builtin_amdgcn_perm(__float_as_uint(xf[2*kk][1]),   __float_as_uint(xf[2*kk][0]),   0x07060302u);
        ax[kk].u[1] = __builtin_amdgcn_perm(__float_as_uint(xf[2*kk][3]),   __float_as_uint(xf[2*kk][2]),   0x07060302u);
        ax[kk].u[2] = __builtin_amdgcn_perm(__float_as_uint(xf[2*kk+1][1]), __float_as_uint(xf[2*kk+1][0]), 0x07060302u);
        ax[kk].u[3] = __builtin_amdgcn_perm(__float_as_uint(xf[2*kk+1][3]), __float_as_uint(xf[2*kk+1][2]), 0x07060302u);
    }
    ax[3].u[0] = __builtin_amdgcn_perm(__float_as_uint(xf[6][1]), __float_as_uint(xf[6][0]), 0x07060302u);
    ax[3].u[1] = __builtin_amdgcn_perm(__float_as_uint(xf[6][3]), __float_as_uint(xf[6][2]), 0x07060302u);
    ax[3].u[2] = ax[3].u[0];   // k>=100 rows of Wx frag are zero
    ax[3].u[3] = ax[3].u[1];
}

#define MFMA(A, Bf, C) __builtin_amdgcn_mfma_f32_16x16x32_bf16((A), (Bf), (C), 0, 0, 0)

// ============ fused RNN v9: 1 wave = 16 rows, no barriers; proj off critical path;
// h stored as separate bf16 hi/lo LDS arrays -> ds_read_b128 feeds MFMA directly ============
__global__ __launch_bounds__(64, 1)
void rnn_v9(const int* __restrict__ tokens, const float* __restrict__ emb,
            const float* __restrict__ Wx, const float* __restrict__ Wh,
            const float* __restrict__ bias, const float* __restrict__ Wfc,
            const float* __restrict__ bfc, float* __restrict__ out)
{
    // H arrays: [row=batch 16][col=unit 64] bf16, col-block XOR swizzle (8-col granular)
    __shared__ __align__(16) unsigned short Hhi[16 * 64];
    __shared__ __align__(16) unsigned short Hlo[16 * 64];
    __shared__ int toks[16 * T_];

    const int l = threadIdx.x;
    const int q = l >> 4, p = l & 15;
    const int R0 = blockIdx.x * 16;

    for (int i = l; i < 16 * T_; i += 64) toks[i] = tokens[R0 * T_ + i];

    // ---- Wx fragments: 1-term RNE ----
    FragU wxh[4][4];
    #pragma unroll
    for (int kk = 0; kk < 4; ++kk)
        #pragma unroll
        for (int n = 0; n < 4; ++n)
            #pragma unroll
            for (int j = 0; j < 8; ++j) {
                int k = 8 * q + j + 32 * kk;
                float v = (k < E_) ? Wx[k * U_ + 16 * n + p] : 0.0f;
                wxh[kk][n].s[j] = bf16_rne(v);
            }
    // ---- Wh fragments: exact hi/lo (3-term recurrence) ----
    FragU whh[2][4], whl[2][4];
    #pragma unroll
    for (int kk = 0; kk < 2; ++kk)
        #pragma unroll
        for (int n = 0; n < 4; ++n)
            #pragma unroll
            for (int j = 0; j < 8; ++j) {
                float v = Wh[(8 * q + j + 32 * kk) * U_ + 16 * n + p];
                split_bf16(v, whh[kk][n].s[j], whl[kk][n].s[j]);
            }

    float bv[4], wf[4];
    #pragma unroll
    for (int n = 0; n < 4; ++n) { bv[n] = bias[16 * n + p]; wf[n] = Wfc[16 * n + p]; }
    const f32x4 z4 = {0.0f, 0.0f, 0.0f, 0.0f};

    // ---- h(0) = 0 (single wave: DS in-order, no barrier needed) ----
    { uint32_t* a = (uint32_t*)Hhi; uint32_t* b = (uint32_t*)Hlo;
      for (int i = l; i < 512; i += 64) { a[i] = 0u; b[i] = 0u; } }

    // read offsets (u16 index): row p, col (8q | 32kk) ^ ((p&7)<<3)  -- 16B aligned
    const int rswz   = (p & 7) << 3;
    const int rdoff0 = p * 64 + ((8 * q)      ^ rswz);
    const int rdoff1 = p * 64 + ((32 + 8 * q) ^ rswz);

    // ---- prologue: P(0) from x(0); x(1) in flight ----
    f32x4 X[7];
    FragU ax[4];
    gather_x(emb + (size_t)toks[p * T_ + 0] * E_, q, X);
    cvt_x(X, ax);
    f32x4 P[4];
    #pragma unroll
    for (int n = 0; n < 4; ++n) {
        f32x4 bn = {bv[n], bv[n], bv[n], bv[n]};
        f32x4 c = MFMA(ax[0].v, wxh[0][n].v, bn);
        c = MFMA(ax[1].v, wxh[1][n].v, c);
        c = MFMA(ax[2].v, wxh[2][n].v, c);
        c = MFMA(ax[3].v, wxh[3][n].v, c);
        P[n] = c;
    }
    gather_x(emb + (size_t)toks[p * T_ + 1] * E_, q, X);
    int tokc = toks[p * T_ + 2];

    // initial h fragments (zeros)
    LdU ah0, ah1, al0, al1;
    ah0.q4 = *(const uint4*)(Hhi + rdoff0);
    ah1.q4 = *(const uint4*)(Hhi + rdoff1);
    al0.q4 = *(const uint4*)(Hlo + rdoff0);
    al1.q4 = *(const uint4*)(Hlo + rdoff1);

    float hl[16];

    for (int t = 0; t < T_; ++t) {
        // x(t+1) fragments (gather landed during previous step); reissue x(t+2)
        FragU axn[4];
        cvt_x(X, axn);
        gather_x(emb + (size_t)tokc * E_, q, X);
        int ti = t + 3; if (ti > T_ - 1) ti = T_ - 1;
        const int tokn = toks[p * T_ + ti];

        // ---- critical path: 3 parallel depth-2 MFMA chains per n ----
        f32x4 acc[4];
        #pragma unroll
        for (int n = 0; n < 4; ++n) {
            f32x4 c1 = MFMA(ah0.v, whh[0][n].v, P[n]);
            c1       = MFMA(ah1.v, whh[1][n].v, c1);
            f32x4 c2 = MFMA(al0.v, whh[0][n].v, z4);
            c2       = MFMA(al1.v, whh[1][n].v, c2);
            f32x4 c3 = MFMA(ah0.v, whl[0][n].v, z4);
            c3       = MFMA(ah1.v, whl[1][n].v, c3);
            acc[n] = (c1 + c2) + c3;
        }

        // ---- tanh + exact hi/lo split + swizzled b16 writes ----
        #pragma unroll
        for (int r = 0; r < 4; ++r) {
            const int row   = 4 * q + r;
            const int wbase = row * 64;
            const int wswz  = (row & 7) << 3;
            #pragma unroll
            for (int n = 0; n < 4; ++n) {
                float h = tanh_fast(acc[n][r]);
                hl[r * 4 + n] = h;
                uint32_t hb  = __float_as_uint(h);
                uint32_t hib = hb & 0xFFFF0000u;
                float rem = h - __uint_as_float(hib);
                const int idx = wbase + ((16 * n + p) ^ wswz);
                Hhi[idx] = (unsigned short)(hb >> 16);
                Hlo[idx] = (unsigned short)(__float_as_uint(rem) >> 16);
            }
        }

        // ---- read h(t) for next step (queues after writes; latency hidden by proj below) ----
        ah0.q4 = *(const uint4*)(Hhi + rdoff0);
        ah1.q4 = *(const uint4*)(Hhi + rdoff1);
        al0.q4 = *(const uint4*)(Hlo + rdoff0);
        al1.q4 = *(const uint4*)(Hlo + rdoff1);

        // ---- proj for t+1 (off critical path) ----
        #pragma unroll
        for (int n = 0; n < 4; ++n) {
            f32x4 bn = {bv[n], bv[n], bv[n], bv[n]};
            f32x4 c = MFMA(axn[0].v, wxh[0][n].v, bn);
            c = MFMA(axn[1].v, wxh[1][n].v, c);
            c = MFMA(axn[2].v, wxh[2][n].v, c);
            c = MFMA(axn[3].v, wxh[3][n].v, c);
            P[n] = c;
        }
        tokc = tokn;
    }

    // ---- logits + sigmoid ----
    #pragma unroll
    for (int r = 0; r < 4; ++r) {
        float part = hl[r * 4 + 0] * wf[0] + hl[r * 4 + 1] * wf[1]
                   + hl[r * 4 + 2] * wf[2] + hl[r * 4 + 3] * wf[3];
        part += __shfl_xor(part, 1);
        part += __shfl_xor(part, 2);
        part += __shfl_xor(part, 4);
        part += __shfl_xor(part, 8);
        if (p == 0) out[R0 + 4 * q + r] = sigmoid_f(part + bfc[0]);
    }
}

extern "C" void kernel_launch(void* const* d_in, const int* in_sizes, int n_in,
                              void* d_out, int out_size, void* d_ws, size_t ws_size,
                              hipStream_t stream) {
    const int*   tokens = (const int*)  d_in[0];
    const float* emb    = (const float*)d_in[1];
    const float* Wx     = (const float*)d_in[2];
    const float* Wh     = (const float*)d_in[3];
    const float* b      = (const float*)d_in[4];
    const float* Wfc    = (const float*)d_in[5];
    const float* bfc    = (const float*)d_in[6];
    float* out          = (float*)d_out;

    rnn_v9<<<B_ / 16, 64, 0, stream>>>(tokens, emb, Wx, Wh, b, Wfc, bfc, out);
}